// Round 4
// baseline (183.693 us; speedup 1.0000x reference)
//
#include <hip/hip_runtime.h>
#include <math.h>

// Problem constants (verified against setup_inputs): E=1024, CTX=1024.
#define EDIM 1024
#define CTXDIM 1024
#define H2 2048
#define NBLK 256

// ws float layout:
//   [0    : 1024)  h first half  = C * relu(emb[x] @ Mw^T + Mb)
//   [1024 : 2048)  h second half = sum_c relu(emb[ctx] @ Mw^T + Mb)
//   [2048 : 3072)  mu
//   [3072 : 4096)  sigma
//   [4096 : 4099)  3 unsigned counters (sync0, sync1, finale) — memset to 0
//   [4100 : ...)   S: S[0]=logdet, S[1]=S_x, S[2..2+C)=pos, S[2+C..)=neg

__device__ __forceinline__ void grid_sync(unsigned* cnt) {
    // release my writes, block-arrive once, spin, acquire.
    __builtin_amdgcn_fence(__ATOMIC_RELEASE, "agent");
    __syncthreads();
    if (threadIdx.x == 0) {
        __hip_atomic_fetch_add(cnt, 1u, __ATOMIC_RELEASE, __HIP_MEMORY_SCOPE_AGENT);
        while (__hip_atomic_load(cnt, __ATOMIC_RELAXED, __HIP_MEMORY_SCOPE_AGENT)
               < (unsigned)NBLK)
            __builtin_amdgcn_s_sleep(1);
    }
    __syncthreads();
    __builtin_amdgcn_fence(__ATOMIC_ACQUIRE, "agent");
}

__global__ __launch_bounds__(1024) void k_fused(
    const float* __restrict__ emb, const float* __restrict__ Mw,
    const float* __restrict__ Mb, const float* __restrict__ Uw,
    const float* __restrict__ Ub, const float* __restrict__ Ww,
    const float* __restrict__ Wb, const float* __restrict__ pmu,
    const float* __restrict__ psig, const int* __restrict__ x,
    const int* __restrict__ ctx, const int* __restrict__ negs,
    int C, int CN, int NEG, int KDIM,
    float* __restrict__ ws, float* __restrict__ out)
{
    const int tid  = threadIdx.x;
    const int w    = tid >> 6;
    const int lane = tid & 63;
    const int b    = blockIdx.x;
    unsigned* cnt  = (unsigned*)(ws + 4096);
    float* Sbuf    = ws + 4100;

    __shared__ float pacc[16];
    __shared__ float pxs[4];
    __shared__ float part[16];

    // ---------------- Phase A: h[2048] ----------------
    // Block owns 4 cols; wave (c,g) = col 4b+c, rows r ≡ g (mod 4) of 1+C rows.
    {
        const int c = w & 3;
        const int g = w >> 2;
        const int j = b * 4 + c;
        const float4* mrow = (const float4*)(Mw + (size_t)j * EDIM);
        const float4 mw0 = mrow[lane];
        const float4 mw1 = mrow[lane + 64];
        const float4 mw2 = mrow[lane + 128];
        const float4 mw3 = mrow[lane + 192];
        const float bj = Mb[j];

        float acc = 0.f, px = 0.f;
        for (int r = g; r <= C; r += 4) {
            const int idx = (r == 0) ? x[0] : ctx[r - 1];
            const float4* e4 = (const float4*)(emb + (size_t)idx * EDIM);
            const float4 a  = e4[lane];
            const float4 bb = e4[lane + 64];
            const float4 d  = e4[lane + 128];
            const float4 e  = e4[lane + 192];
            float s = a.x*mw0.x + a.y*mw0.y + a.z*mw0.z + a.w*mw0.w;
            s += bb.x*mw1.x + bb.y*mw1.y + bb.z*mw1.z + bb.w*mw1.w;
            s += d.x*mw2.x + d.y*mw2.y + d.z*mw2.z + d.w*mw2.w;
            s += e.x*mw3.x + e.y*mw3.y + e.z*mw3.z + e.w*mw3.w;
#pragma unroll
            for (int m = 32; m >= 1; m >>= 1) s += __shfl_xor(s, m);
            const float v = fmaxf(s + bj, 0.f);
            if (r == 0) px = (float)C * v;
            else        acc += v;
        }
        if (lane == 0) {
            pacc[w] = acc;
            if (g == 0) pxs[c] = px;
        }
        __syncthreads();
        if (tid < 4) {
            const int jj = b * 4 + tid;
            ws[jj]          = pxs[tid];
            ws[CTXDIM + jj] = pacc[tid] + pacc[tid + 4] + pacc[tid + 8] + pacc[tid + 12];
        }
    }

    grid_sync(&cnt[0]);

    // ---------------- Phase B: mu, sigma ----------------
    // Blocks 0..127: mu rows 8b..8b+7. Blocks 128..255: sigma rows.
    // Wave pair (w>>1 = local row, w&1 = which half of the 2048-dot).
    {
        const bool is_mu = (b < 128);
        const int rr   = (b & 127) * 8 + (w >> 1);
        const int half = w & 1;
        const float4* W4 = (const float4*)((is_mu ? Uw : Ww)
                            + (size_t)rr * H2 + (size_t)half * 1024);
        const float4* h4 = (const float4*)(ws + half * 1024);
        float s = 0.f;
#pragma unroll
        for (int k = 0; k < 4; ++k) {
            const float4 wv = W4[lane + 64 * k];
            const float4 hv = h4[lane + 64 * k];
            s += wv.x*hv.x + wv.y*hv.y + wv.z*hv.z + wv.w*hv.w;
        }
#pragma unroll
        for (int m = 32; m >= 1; m >>= 1) s += __shfl_xor(s, m);
        if (lane == 0) part[w] = s;
        __syncthreads();
        if ((w & 1) == 0 && lane == 0) {
            const float tot = part[w] + part[w + 1];
            if (is_mu) {
                ws[2048 + rr] = tot + Ub[rr];
            } else {
                const float v = tot + Wb[rr];
                ws[3072 + rr] = fmaxf(v, 0.f) + log1pf(expf(-fabsf(v)));  // softplus
            }
        }
    }

    grid_sync(&cnt[1]);

    // ---------------- Phase C: per-candidate S + fused finale ----------------
    // Task t = b + 256*w for w<3. t0: logdet; t1: x; [2,2+C): pos; rest: neg.
    {
        const int ntask = 2 + C + CN;
        const int t = b + NBLK * w;
        const bool have = (w < 3) && (t < ntask);
        float acc = 0.f;
        if (have) {
            if (t == 0) {          // logdet = sum log sigma
#pragma unroll
                for (int k = 0; k < 16; ++k) acc += logf(ws[3072 + lane + 64 * k]);
            } else {
                int idx;
                if (t == 1)          idx = x[0];
                else if (t < 2 + C)  idx = ctx[t - 2];
                else                 idx = negs[t - 2 - C];
                const float4* m4  = (const float4*)(pmu  + (size_t)idx * CTXDIM);
                const float4* s4  = (const float4*)(psig + (size_t)idx * CTXDIM);
                const float4* mu4 = (const float4*)(ws + 2048);
                const float4* sg4 = (const float4*)(ws + 3072);
#pragma unroll
                for (int k = 0; k < 4; ++k) {
                    const int i = lane + 64 * k;
                    const float4 m  = m4[i];
                    const float4 sv = s4[i];
                    const float4 mu = mu4[i];
                    const float4 sg = sg4[i];
                    { const float s2 = sv.x*sv.x; const float dd = m.x-mu.x; acc += (sg.x + dd*dd)/s2 + logf(s2); }
                    { const float s2 = sv.y*sv.y; const float dd = m.y-mu.y; acc += (sg.y + dd*dd)/s2 + logf(s2); }
                    { const float s2 = sv.z*sv.z; const float dd = m.z-mu.z; acc += (sg.z + dd*dd)/s2 + logf(s2); }
                    { const float s2 = sv.w*sv.w; const float dd = m.w-mu.w; acc += (sg.w + dd*dd)/s2 + logf(s2); }
                }
            }
#pragma unroll
            for (int m = 32; m >= 1; m >>= 1) acc += __shfl_xor(acc, m);
        }

        int win = 0;
        if (have && lane == 0) {
            __hip_atomic_store(&Sbuf[t], acc, __ATOMIC_RELAXED, __HIP_MEMORY_SCOPE_AGENT);
            const unsigned old = __hip_atomic_fetch_add(&cnt[2], 1u,
                                   __ATOMIC_ACQ_REL, __HIP_MEMORY_SCOPE_AGENT);
            win = (old == (unsigned)(ntask - 1));
        }
        win = __shfl(win, 0);
        if (win) {
            float lik = 0.f;
            for (int i = lane; i < CN; i += 64) {
                const float sn = __hip_atomic_load(&Sbuf[2 + C + i],
                                   __ATOMIC_RELAXED, __HIP_MEMORY_SCOPE_AGENT);
                const float sp = __hip_atomic_load(&Sbuf[2 + i / NEG],
                                   __ATOMIC_RELAXED, __HIP_MEMORY_SCOPE_AGENT);
                lik += fmaxf(0.f, 0.5f * (sn - sp) + 1.0f);   // kl_neg - kl_pos + 1
            }
#pragma unroll
            for (int m = 32; m >= 1; m >>= 1) lik += __shfl_xor(lik, m);
            if (lane == 0) {
                const float ld = __hip_atomic_load(&Sbuf[0],
                                   __ATOMIC_RELAXED, __HIP_MEMORY_SCOPE_AGENT);
                const float sx = __hip_atomic_load(&Sbuf[1],
                                   __ATOMIC_RELAXED, __HIP_MEMORY_SCOPE_AGENT);
                out[0] = lik - 0.5f * (sx - (float)KDIM - ld);  // - kl_prior
            }
        }
    }
}

extern "C" void kernel_launch(void* const* d_in, const int* in_sizes, int n_in,
                              void* d_out, int out_size, void* d_ws, size_t ws_size,
                              hipStream_t stream) {
    const int*   x    = (const int*)d_in[0];
    const int*   ctx  = (const int*)d_in[1];
    const int*   negs = (const int*)d_in[2];
    const float* emb  = (const float*)d_in[3];
    const float* Mw   = (const float*)d_in[4];
    const float* Mb   = (const float*)d_in[5];
    const float* Uw   = (const float*)d_in[6];
    const float* Ub   = (const float*)d_in[7];
    const float* Ww   = (const float*)d_in[8];
    const float* Wb   = (const float*)d_in[9];
    const float* pmu  = (const float*)d_in[10];
    const float* psig = (const float*)d_in[11];
    float* ws  = (float*)d_ws;
    float* out = (float*)d_out;

    const int C    = in_sizes[1];          // 50
    const int CN   = in_sizes[2];          // 500
    const int NEG  = CN / C;               // 10
    const int KDIM = in_sizes[5];          // CTX = 1024

    // Deterministically re-zero the 3 sync counters each launch.
    (void)hipMemsetAsync((char*)d_ws + 4096 * sizeof(float), 0,
                         3 * sizeof(unsigned), stream);
    k_fused<<<NBLK, 1024, 0, stream>>>(emb, Mw, Mb, Uw, Ub, Ww, Wb, pmu, psig,
                                       x, ctx, negs, C, CN, NEG, KDIM, ws, out);
}

// Round 5
// 25.610 us; speedup vs baseline: 7.1727x; 7.1727x over previous
//
#include <hip/hip_runtime.h>
#include <math.h>

// Problem constants (verified against setup_inputs): E=1024, CTX=1024.
#define EDIM 1024
#define CTXDIM 1024
#define H2 2048

// ws float layout:
//   [0    : 1024)  h first half  = C * relu(emb[x] @ Mw^T + Mb)
//   [1024 : 2048)  h second half = sum_c relu(emb[ctx] @ Mw^T + Mb)
//   [2048 : 3072)  mu
//   [3072 : 4096)  sigma
//   [4096 : 4099)  unsigned counters; cnt[2] = k_S arrival counter
//   [4100 : ...)   S: S[0]=logdet, S[1]=S_x, S[2..2+C)=pos, S[2+C..)=neg

// ---------------- Kernel 1: h[2048] ----------------
// 256 blocks x 1024 thr (16 waves). Block owns 4 cols; wave (c,g) = col 4b+c,
// rows r ≡ g (mod 4) of the 1+C input rows (row 0 = x). ctx indices preloaded
// into LDS so the row loop has no dependent global scalar loads.
__global__ __launch_bounds__(1024) void k_h(
    const float* __restrict__ emb, const float* __restrict__ Mw,
    const float* __restrict__ Mb, const int* __restrict__ x,
    const int* __restrict__ ctx, int C, float* __restrict__ ws)
{
    __shared__ int   idxs[64];
    __shared__ float pacc[16];
    __shared__ float pxs[4];
    const int tid  = threadIdx.x;
    const int w    = tid >> 6;
    const int lane = tid & 63;
    const int c    = w & 3;
    const int g    = w >> 2;
    const int j    = blockIdx.x * 4 + c;

    if (tid <= C) idxs[tid] = (tid == 0) ? x[0] : ctx[tid - 1];

    const float4* mrow = (const float4*)(Mw + (size_t)j * EDIM);
    const float4 mw0 = mrow[lane];
    const float4 mw1 = mrow[lane + 64];
    const float4 mw2 = mrow[lane + 128];
    const float4 mw3 = mrow[lane + 192];
    const float bj = Mb[j];
    __syncthreads();

    float acc = 0.f, px = 0.f;
#pragma unroll 2
    for (int r = g; r <= C; r += 4) {
        const int idx = idxs[r];
        const float4* e4 = (const float4*)(emb + (size_t)idx * EDIM);
        const float4 a  = e4[lane];
        const float4 bb = e4[lane + 64];
        const float4 d  = e4[lane + 128];
        const float4 e  = e4[lane + 192];
        float s = a.x*mw0.x + a.y*mw0.y + a.z*mw0.z + a.w*mw0.w;
        s += bb.x*mw1.x + bb.y*mw1.y + bb.z*mw1.z + bb.w*mw1.w;
        s += d.x*mw2.x + d.y*mw2.y + d.z*mw2.z + d.w*mw2.w;
        s += e.x*mw3.x + e.y*mw3.y + e.z*mw3.z + e.w*mw3.w;
#pragma unroll
        for (int m = 32; m >= 1; m >>= 1) s += __shfl_xor(s, m);
        const float v = fmaxf(s + bj, 0.f);
        if (r == 0) px = (float)C * v;   // x-row appears only in group 0
        else        acc += v;
    }
    if (lane == 0) {
        pacc[w] = acc;
        if (g == 0) pxs[c] = px;
    }
    __syncthreads();
    if (tid < 4) {
        const int jj = blockIdx.x * 4 + tid;
        ws[jj]          = pxs[tid];
        ws[CTXDIM + jj] = pacc[tid] + pacc[tid + 4] + pacc[tid + 8] + pacc[tid + 12];
    }
}

// ---------------- Kernel 2: mu, sigma ----------------
// 256 blocks x 512 thr (8 waves). Global wave W = 8b+w handles row W:
// W<1024 -> mu row W; else sigma row W-1024. Full 2048-dot per wave.
__global__ __launch_bounds__(512) void k_musig(
    const float* __restrict__ Uw, const float* __restrict__ Ub,
    const float* __restrict__ Ww, const float* __restrict__ Wb,
    float* __restrict__ ws)
{
    if (blockIdx.x == 0 && threadIdx.x == 0) {
        __hip_atomic_store((unsigned*)(ws + 4096) + 2, 0u,
                           __ATOMIC_RELAXED, __HIP_MEMORY_SCOPE_AGENT);
    }
    __shared__ float4 hbuf[512];                   // h (2048 f32)
    const int tid = threadIdx.x;
    hbuf[tid] = ((const float4*)ws)[tid];
    __syncthreads();

    const int w = tid >> 6, lane = tid & 63;
    const int W = blockIdx.x * 8 + w;              // 0..2047
    const bool is_mu = (W < CTXDIM);
    const int rr = W & (CTXDIM - 1);
    const float4* Wr4 = (const float4*)((is_mu ? Uw : Ww) + (size_t)rr * H2);

    float s = 0.f;
#pragma unroll
    for (int k = 0; k < 8; ++k) {
        const float4 wv = Wr4[lane + 64 * k];
        const float4 hv = hbuf[lane + 64 * k];
        s += wv.x*hv.x + wv.y*hv.y + wv.z*hv.z + wv.w*hv.w;
    }
#pragma unroll
    for (int m = 32; m >= 1; m >>= 1) s += __shfl_xor(s, m);

    if (lane == 0) {
        if (is_mu) {
            ws[2048 + rr] = s + Ub[rr];
        } else {
            const float v = s + Wb[rr];
            ws[3072 + rr] = fmaxf(v, 0.f) + log1pf(expf(-fabsf(v)));  // softplus
        }
    }
}

// ---------------- Kernel 3: per-candidate S + fused finale ----------------
// 4 tasks per 256-thr block. t0: logdet; t1: x; [2,2+C): pos; rest: neg.
// mu/sigma staged in LDS (shared by the 4 waves). ONE release fence + ONE
// relaxed arrival RMW per block (wave-uniform); last block's wave 0 finishes.
__global__ __launch_bounds__(256) void k_S(
    const float* __restrict__ pmu, const float* __restrict__ psig,
    const int* __restrict__ x, const int* __restrict__ ctx,
    const int* __restrict__ negs, int C, int CN, int NEG, int KDIM,
    int nblk, float* __restrict__ ws, float* __restrict__ out)
{
    __shared__ float musig[2048];                  // [0:1024) mu, [1024:2048) sigma
    const int tid = threadIdx.x;
    float4* ms4 = (float4*)musig;
    ms4[tid]       = ((const float4*)(ws + 2048))[tid];
    ms4[tid + 256] = ((const float4*)(ws + 2048))[tid + 256];
    __syncthreads();

    const int w = tid >> 6, lane = tid & 63;
    const int t = blockIdx.x * 4 + w;
    const int ntask = 2 + C + CN;
    float* Sbuf = ws + 4100;
    unsigned* cnt = (unsigned*)(ws + 4096) + 2;

    if (t < ntask) {
        float acc = 0.f;
        if (t == 0) {          // logdet = sum log sigma
#pragma unroll
            for (int k = 0; k < 16; ++k) acc += logf(musig[1024 + lane + 64 * k]);
        } else {
            int idx;
            if (t == 1)          idx = x[0];
            else if (t < 2 + C)  idx = ctx[t - 2];
            else                 idx = negs[t - 2 - C];
            const float4* m4 = (const float4*)(pmu  + (size_t)idx * CTXDIM);
            const float4* s4 = (const float4*)(psig + (size_t)idx * CTXDIM);
#pragma unroll
            for (int k = 0; k < 4; ++k) {
                const int i = lane + 64 * k;
                const float4 m  = m4[i];
                const float4 sv = s4[i];
                const float4 mu = ms4[i];
                const float4 sg = ms4[256 + i];
                { const float s2 = sv.x*sv.x; const float dd = m.x-mu.x; acc += (sg.x + dd*dd)/s2 + logf(s2); }
                { const float s2 = sv.y*sv.y; const float dd = m.y-mu.y; acc += (sg.y + dd*dd)/s2 + logf(s2); }
                { const float s2 = sv.z*sv.z; const float dd = m.z-mu.z; acc += (sg.z + dd*dd)/s2 + logf(s2); }
                { const float s2 = sv.w*sv.w; const float dd = m.w-mu.w; acc += (sg.w + dd*dd)/s2 + logf(s2); }
            }
        }
#pragma unroll
        for (int m = 32; m >= 1; m >>= 1) acc += __shfl_xor(acc, m);
        if (lane == 0)
            __hip_atomic_store(&Sbuf[t], acc, __ATOMIC_RELAXED, __HIP_MEMORY_SCOPE_AGENT);
    }

    __syncthreads();                // all 4 waves' Sbuf stores issued & complete
    if (w == 0) {                   // wave-uniform from here
        __builtin_amdgcn_fence(__ATOMIC_RELEASE, "agent");   // one L2 writeback per block
        int win = 0;
        if (lane == 0) {
            const unsigned old = __hip_atomic_fetch_add(cnt, 1u,
                                   __ATOMIC_RELAXED, __HIP_MEMORY_SCOPE_AGENT);
            win = (old == (unsigned)(nblk - 1));
        }
        win = __shfl(win, 0);
        if (win) {
            __builtin_amdgcn_fence(__ATOMIC_ACQUIRE, "agent");
            float lik = 0.f;
            for (int i = lane; i < CN; i += 64) {
                const float sn = __hip_atomic_load(&Sbuf[2 + C + i],
                                   __ATOMIC_RELAXED, __HIP_MEMORY_SCOPE_AGENT);
                const float sp = __hip_atomic_load(&Sbuf[2 + i / NEG],
                                   __ATOMIC_RELAXED, __HIP_MEMORY_SCOPE_AGENT);
                lik += fmaxf(0.f, 0.5f * (sn - sp) + 1.0f);   // kl_neg - kl_pos + 1
            }
#pragma unroll
            for (int m = 32; m >= 1; m >>= 1) lik += __shfl_xor(lik, m);
            if (lane == 0) {
                const float ld = __hip_atomic_load(&Sbuf[0],
                                   __ATOMIC_RELAXED, __HIP_MEMORY_SCOPE_AGENT);
                const float sx = __hip_atomic_load(&Sbuf[1],
                                   __ATOMIC_RELAXED, __HIP_MEMORY_SCOPE_AGENT);
                out[0] = lik - 0.5f * (sx - (float)KDIM - ld);  // - kl_prior
            }
        }
    }
}

extern "C" void kernel_launch(void* const* d_in, const int* in_sizes, int n_in,
                              void* d_out, int out_size, void* d_ws, size_t ws_size,
                              hipStream_t stream) {
    const int*   x    = (const int*)d_in[0];
    const int*   ctx  = (const int*)d_in[1];
    const int*   negs = (const int*)d_in[2];
    const float* emb  = (const float*)d_in[3];
    const float* Mw   = (const float*)d_in[4];
    const float* Mb   = (const float*)d_in[5];
    const float* Uw   = (const float*)d_in[6];
    const float* Ub   = (const float*)d_in[7];
    const float* Ww   = (const float*)d_in[8];
    const float* Wb   = (const float*)d_in[9];
    const float* pmu  = (const float*)d_in[10];
    const float* psig = (const float*)d_in[11];
    float* ws  = (float*)d_ws;
    float* out = (float*)d_out;

    const int C    = in_sizes[1];          // 50
    const int CN   = in_sizes[2];          // 500
    const int NEG  = CN / C;               // 10
    const int KDIM = in_sizes[5];          // CTX = 1024

    k_h<<<CTXDIM / 4, 1024, 0, stream>>>(emb, Mw, Mb, x, ctx, C, ws);
    k_musig<<<256, 512, 0, stream>>>(Uw, Ub, Ww, Wb, ws);
    const int ntask = 2 + C + CN;
    const int nblk  = (ntask + 3) / 4;
    k_S<<<nblk, 256, 0, stream>>>(pmu, psig, x, ctx, negs,
                                  C, CN, NEG, KDIM, nblk, ws, out);
}